// Round 1
// baseline (154.593 us; speedup 1.0000x reference)
//
#include <hip/hip_runtime.h>
#include <stdint.h>

// E8P codebook quantization: for each of N points (8-dim fp32), find
// argmax_c (2*x.g_c - ||g_c||^2) over 256 codewords; output Xq=grid[idx]
// (fp32) and idx.
//
// VALU-bound brute force: 256 cw * 8 dims FMA per point. Codebook rows are
// loaded at wave-uniform addresses (scalar-pipe s_load candidates); the *2
// is folded into X once (exact, power-of-two). float2 math to invite
// v_pk_fma_f32 packed fp32.

#define DIM 8
#define NCODES 256
#define PPT 4   // points per thread, interleaved at wave granularity

// MODE: 0 = Xq only; 1 = idx as uint8 bytes after Xq; 2 = idx as float after Xq
template <int MODE>
__global__ __launch_bounds__(256)
void e8_quant_kernel(const float* __restrict__ X,
                     const float* __restrict__ grid,
                     const float* __restrict__ gnorm,
                     float* __restrict__ xq_out,
                     void* __restrict__ idx_out,
                     int N)
{
    const int tid  = blockIdx.x * blockDim.x + threadIdx.x;
    const int lane = threadIdx.x & 63;
    const long wbase = (long)(tid >> 6) * (64 * PPT);

    // ---- load PPT points, pre-scaled by 2 (exact) ----
    float2 x2[PPT][4];
    #pragma unroll
    for (int p = 0; p < PPT; ++p) {
        const long pt = wbase + (long)p * 64 + lane;
        float4 a = make_float4(0.f, 0.f, 0.f, 0.f);
        float4 b = a;
        if (pt < N) {
            const float4* src = reinterpret_cast<const float4*>(X + pt * DIM);
            a = src[0];
            b = src[1];
        }
        x2[p][0] = make_float2(2.f * a.x, 2.f * a.y);
        x2[p][1] = make_float2(2.f * a.z, 2.f * a.w);
        x2[p][2] = make_float2(2.f * b.x, 2.f * b.y);
        x2[p][3] = make_float2(2.f * b.z, 2.f * b.w);
    }

    float best[PPT];
    int   bidx[PPT];
    #pragma unroll
    for (int p = 0; p < PPT; ++p) { best[p] = -3.4e38f; bidx[p] = 0; }

    // ---- brute-force scan over 256 codewords ----
    for (int c = 0; c < NCODES; ++c) {
        // wave-uniform address: candidate for scalar loads
        const float2* g = reinterpret_cast<const float2*>(grid + c * DIM);
        const float2 g0 = g[0], g1 = g[1], g2 = g[2], g3 = g[3];
        const float  nb = gnorm[c];
        #pragma unroll
        for (int p = 0; p < PPT; ++p) {
            float2 acc = x2[p][0] * g0;      // hope: v_pk_fma_f32 chain
            acc += x2[p][1] * g1;
            acc += x2[p][2] * g2;
            acc += x2[p][3] * g3;
            const float s = (acc.x + acc.y) - nb;   // == 2*x.g - ||g||^2
            const bool gt = s > best[p];            // strict >: first max wins (jnp.argmax)
            best[p] = gt ? s : best[p];
            bidx[p] = gt ? c : bidx[p];
        }
    }

    // ---- write Xq = grid[idx] and idx ----
    #pragma unroll
    for (int p = 0; p < PPT; ++p) {
        const long pt = wbase + (long)p * 64 + lane;
        if (pt >= N) continue;
        const float4* gr = reinterpret_cast<const float4*>(grid + bidx[p] * DIM);
        const float4 q0 = gr[0];
        const float4 q1 = gr[1];
        float4* dst = reinterpret_cast<float4*>(xq_out + pt * DIM);
        dst[0] = q0;
        dst[1] = q1;
        if (MODE == 2) {
            reinterpret_cast<float*>(idx_out)[pt] = (float)bidx[p];
        } else if (MODE == 1) {
            reinterpret_cast<uint8_t*>(idx_out)[pt] = (uint8_t)bidx[p];
        }
    }
}

extern "C" void kernel_launch(void* const* d_in, const int* in_sizes, int n_in,
                              void* d_out, int out_size, void* d_ws, size_t ws_size,
                              hipStream_t stream)
{
    const float* X     = (const float*)d_in[0];
    const float* grid  = (const float*)d_in[1];
    const float* gnorm = (const float*)d_in[2];

    const int N = in_sizes[0] / DIM;

    float* xq   = (float*)d_out;
    void*  idxp = (void*)(xq + (size_t)N * DIM);

    const int threads = (N + PPT - 1) / PPT;
    const int blocks  = (threads + 255) / 256;

    const long xq_elems = (long)N * DIM;
    if ((long)out_size >= xq_elems + N) {
        // idx stored as float elements after Xq
        e8_quant_kernel<2><<<blocks, 256, 0, stream>>>(X, grid, gnorm, xq, idxp, N);
    } else if ((long)out_size > xq_elems) {
        // idx stored as raw uint8 bytes after Xq
        e8_quant_kernel<1><<<blocks, 256, 0, stream>>>(X, grid, gnorm, xq, idxp, N);
    } else {
        // harness only validates Xq
        e8_quant_kernel<0><<<blocks, 256, 0, stream>>>(X, grid, gnorm, xq, idxp, N);
    }
}

// Round 2
// 104.492 us; speedup vs baseline: 1.4795x; 1.4795x over previous
//
#include <hip/hip_runtime.h>
#include <stdint.h>

// E8P 256-codeword quantizer, analytic decode.
//
// Codebook structure (compile-time known from the reference builder):
//   idx   0..112 : integer E8 points: zero vector + all +-e_i +- e_j (i<j),
//                  ranked by cartesian_prod key over digits {-2,-1,0,1}.
//   idx 113..240 : half points: all coords +-0.5, even # of negatives,
//                  ranked by cartesian_prod key over digits {-1.5,-.5,.5,1.5}.
//   idx 241..255 : 15 extra rows = 5 bases {012,014,034,234,123} x tails {5,6,7}.
//
// scores s_c = 2 x.g_c - ||g_c||^2. Class maxima in closed form:
//   pair : 2(a(1)+a(2)) - 2          (a = |x|, top-2)
//   zero : 0
//   half : sum|x| - 2               (minus 2*min|x| if sign-parity odd)
//   extra: 2(max base + max tail) - 4
// Near-tie guard: if best - runnerup <= TAU (or any x_d == +-0), fall back to
// the round-1 brute force (verified absmax==0) for that lane.

#define DIM 8
#define NCODES 256

struct Tables {
    unsigned char pair_idx[256]; // [((lo*8+hi)*2+neg_lo)*2+neg_hi]
    unsigned char half_idx[256]; // [negmask]; even-parity entries valid
    unsigned char zero_idx;
};

constexpr Tables make_tables() {
    Tables t{};
    // ---- integer block: zero + 112 pair points, ranked by lex digit key ----
    unsigned key[113] = {};
    int pi[113] = {}, pj[113] = {}, psi[113] = {}, psj[113] = {};
    int n = 0;
    { // zero vector: all digits 2 (value 0)
        unsigned k = 0;
        for (int d = 0; d < 8; ++d) k = k * 4u + 2u;
        key[n] = k; pi[n] = -1; pj[n] = -1; psi[n] = 0; psj[n] = 0; ++n;
    }
    for (int i = 0; i < 8; ++i)
        for (int j = i + 1; j < 8; ++j)
            for (int a = 0; a < 2; ++a)       // a=1 -> coord i is -1 (digit 1), else +1 (digit 3)
                for (int b = 0; b < 2; ++b) {
                    unsigned k = 0;
                    for (int d = 0; d < 8; ++d) {
                        unsigned dig = 2u;
                        if (d == i) dig = a ? 1u : 3u;
                        if (d == j) dig = b ? 1u : 3u;
                        k = k * 4u + dig;
                    }
                    key[n] = k; pi[n] = i; pj[n] = j; psi[n] = a; psj[n] = b; ++n;
                }
    for (int p = 1; p < n; ++p) { // insertion sort by key
        unsigned kk = key[p]; int a = pi[p], b = pj[p], c = psi[p], d2 = psj[p];
        int q = p - 1;
        while (q >= 0 && key[q] > kk) {
            key[q+1]=key[q]; pi[q+1]=pi[q]; pj[q+1]=pj[q]; psi[q+1]=psi[q]; psj[q+1]=psj[q]; --q;
        }
        key[q+1]=kk; pi[q+1]=a; pj[q+1]=b; psi[q+1]=c; psj[q+1]=d2;
    }
    for (int r = 0; r < n; ++r) {
        if (pi[r] < 0) t.zero_idx = (unsigned char)r;
        else t.pair_idx[(((pi[r]*8 + pj[r])*2 + psi[r])*2) + psj[r]] = (unsigned char)r;
    }
    // ---- half block: even-popcount sign masks, digit neg->1, pos->2 ----
    unsigned hkey[128] = {}; int hm[128] = {}; int hn = 0;
    for (int m = 0; m < 256; ++m) {
        int pc = 0; for (int d = 0; d < 8; ++d) pc += (m >> d) & 1;
        if (pc & 1) continue;
        unsigned k = 0;
        for (int d = 0; d < 8; ++d) k = k * 4u + (((m >> d) & 1) ? 1u : 2u);
        hkey[hn] = m >= 0 ? k : k; hkey[hn] = k; hm[hn] = m; ++hn;
    }
    for (int p = 1; p < hn; ++p) {
        unsigned kk = hkey[p]; int mm = hm[p]; int q = p - 1;
        while (q >= 0 && hkey[q] > kk) { hkey[q+1]=hkey[q]; hm[q+1]=hm[q]; --q; }
        hkey[q+1]=kk; hm[q+1]=mm;
    }
    for (int r = 0; r < hn; ++r) t.half_idx[hm[r]] = (unsigned char)(113 + r);
    return t;
}

constexpr Tables h_tab = make_tables();
__constant__ Tables g_tab = h_tab;

// MODE: 0 = Xq only; 1 = idx as uint8 bytes after Xq; 2 = idx as float after Xq
template <int MODE>
__global__ __launch_bounds__(256)
void e8_decode_kernel(const float* __restrict__ X,
                      const float* __restrict__ grid,
                      const float* __restrict__ gnorm,
                      float* __restrict__ xq_out,
                      void* __restrict__ idx_out,
                      int N)
{
    const long pt = (long)blockIdx.x * blockDim.x + threadIdx.x;
    if (pt >= N) return;

    const float4* xsrc = reinterpret_cast<const float4*>(X + pt * DIM);
    const float4 xa = xsrc[0];
    const float4 xb = xsrc[1];
    float x[8] = {xa.x, xa.y, xa.z, xa.w, xb.x, xb.y, xb.z, xb.w};

    float a[8]; uint32_t sb[8];
    #pragma unroll
    for (int d = 0; d < 8; ++d) {
        const uint32_t u = __float_as_uint(x[d]);
        sb[d] = u >> 31;
        a[d] = __uint_as_float(u & 0x7fffffffu);
    }
    uint32_t mask = 0, par = 0;
    #pragma unroll
    for (int d = 0; d < 8; ++d) { mask |= sb[d] << d; par ^= sb[d]; }
    const bool odd = (par != 0);

    // sequential sum of |x| (matches reference's d-ascending accumulation order)
    float S = a[0];
    #pragma unroll
    for (int d = 1; d < 8; ++d) S += a[d];

    // min + argmin (first occurrence wins)
    float mn = a[0]; int mi = 0;
    #pragma unroll
    for (int d = 1; d < 8; ++d) { const bool lt = a[d] < mn; mn = lt ? a[d] : mn; mi = lt ? d : mi; }
    float mn2 = 3.0e38f;
    #pragma unroll
    for (int d = 0; d < 8; ++d) { const float v = (d == mi) ? 3.0e38f : a[d]; mn2 = fminf(mn2, v); }

    // top-3 of |x| (indices for top-2)
    float m1 = a[0]; int i1 = 0;
    #pragma unroll
    for (int d = 1; d < 8; ++d) { const bool gt = a[d] > m1; m1 = gt ? a[d] : m1; i1 = gt ? d : i1; }
    float m2 = -3.0e38f; int i2 = 0;
    #pragma unroll
    for (int d = 0; d < 8; ++d) {
        const float v = (d == i1) ? -3.0e38f : a[d];
        const bool gt = v > m2; m2 = gt ? v : m2; i2 = gt ? d : i2;
    }
    float m3 = -3.0e38f;
    #pragma unroll
    for (int d = 0; d < 8; ++d) {
        const float v = (d == i1 || d == i2) ? -3.0e38f : a[d];
        m3 = fmaxf(m3, v);
    }

    // ---- class champion scores ----
    const float s_pair = fmaf(2.0f, m1 + m2, -2.0f);
    const float s_half = odd ? (fmaf(-2.0f, mn, S) - 2.0f) : (S - 2.0f);

    const float y01 = x[0] + x[1];
    float b[5];
    b[0] = y01 + x[2];            // {0,1,2}  left-assoc, matches reference order
    b[1] = y01 + x[4];            // {0,1,4}
    b[2] = (x[0] + x[3]) + x[4];  // {0,3,4}
    b[3] = (x[2] + x[3]) + x[4];  // {2,3,4}
    b[4] = (x[1] + x[2]) + x[3];  // {1,2,3}
    float bm = b[0]; int bi = 0;
    #pragma unroll
    for (int k = 1; k < 5; ++k) { const bool gt = b[k] > bm; bm = gt ? b[k] : bm; bi = gt ? k : bi; }
    float b2nd = -3.0e38f;
    #pragma unroll
    for (int k = 0; k < 5; ++k) { const float v = (k == bi) ? -3.0e38f : b[k]; b2nd = fmaxf(b2nd, v); }
    float tm = x[5]; int ti = 0;
    { const bool gt = x[6] > tm; tm = gt ? x[6] : tm; ti = gt ? 1 : ti; }
    { const bool gt = x[7] > tm; tm = gt ? x[7] : tm; ti = gt ? 2 : ti; }
    const float t2 = fmaxf(fminf(fmaxf(x[5], x[6]), x[7]), fminf(x[5], x[6])); // median of 3
    const float s_extra = fmaf(2.0f, bm + tm, -4.0f);

    // ---- within-class runner-ups (upper bounds) for the tie guard ----
    const float r_pair  = fmaf(2.0f, m1 + m3, -2.0f);
    const float r_half  = odd ? (fmaf(-2.0f, mn2, S) - 2.0f)
                              : (fmaf(-2.0f, mn + mn2, S) - 2.0f);
    const float r_extra = fmaf(2.0f, fmaxf(b2nd + tm, bm + t2), -4.0f);

    // ---- codeword indices ----
    const int lo = (i1 < i2) ? i1 : i2;
    const int hi = (i1 < i2) ? i2 : i1;
    const uint32_t slo = (mask >> lo) & 1u;
    const uint32_t shi = (mask >> hi) & 1u;
    const int idx_pair  = g_tab.pair_idx[(((lo << 3) + hi) << 2) + (int)((slo << 1) | shi)];
    const uint32_t hmask = odd ? (mask ^ (1u << mi)) : mask;
    const int idx_half  = g_tab.half_idx[hmask & 255u];
    const int idx_extra = 241 + ti * 5 + bi;
    const int idx_zero  = g_tab.zero_idx;

    // ---- merge 4 candidates; track best / second-best ----
    float best = s_pair; int bidx = idx_pair; float sec = -3.0e38f;
    {
        const float s = 0.0f; const int id = idx_zero;
        const bool gt = s > best;
        const bool take = gt || (s == best && id < bidx);
        sec = fmaxf(sec, gt ? best : s);
        best = gt ? s : best;
        bidx = take ? id : bidx;
    }
    {
        const float s = s_half; const int id = idx_half;
        const bool gt = s > best;
        const bool take = gt || (s == best && id < bidx);
        sec = fmaxf(sec, gt ? best : s);
        best = gt ? s : best;
        bidx = take ? id : bidx;
    }
    {
        const float s = s_extra; const int id = idx_extra;
        const bool gt = s > best;
        const bool take = gt || (s == best && id < bidx);
        sec = fmaxf(sec, gt ? best : s);
        best = gt ? s : best;
        bidx = take ? id : bidx;
    }
    sec = fmaxf(fmaxf(sec, r_pair), fmaxf(r_half, r_extra));

    // ---- near-tie / degenerate guard: brute-force those lanes (round-1 math) ----
    const bool fb = !((best - sec) > 2e-4f) || !(mn > 0.0f);
    if (__any(fb)) {
        if (fb) {
            float2 xv[4];
            #pragma unroll
            for (int q = 0; q < 4; ++q)
                xv[q] = make_float2(2.0f * x[2*q], 2.0f * x[2*q + 1]);
            float bb = -3.4e38f; int bbi = 0;
            for (int c = 0; c < NCODES; ++c) {
                const float2* g2 = reinterpret_cast<const float2*>(grid + c * DIM);
                float2 acc = xv[0] * g2[0];
                acc += xv[1] * g2[1];
                acc += xv[2] * g2[2];
                acc += xv[3] * g2[3];
                const float s = (acc.x + acc.y) - gnorm[c];
                const bool gt = s > bb;
                bb = gt ? s : bb; bbi = gt ? c : bbi;
            }
            bidx = bbi;
        }
    }

    // ---- outputs ----
    const float4* gr = reinterpret_cast<const float4*>(grid + (long)bidx * DIM);
    const float4 q0 = gr[0];
    const float4 q1 = gr[1];
    float4* dst = reinterpret_cast<float4*>(xq_out + pt * DIM);
    dst[0] = q0;
    dst[1] = q1;
    if (MODE == 2) {
        reinterpret_cast<float*>(idx_out)[pt] = (float)bidx;
    } else if (MODE == 1) {
        reinterpret_cast<uint8_t*>(idx_out)[pt] = (uint8_t)bidx;
    }
}

extern "C" void kernel_launch(void* const* d_in, const int* in_sizes, int n_in,
                              void* d_out, int out_size, void* d_ws, size_t ws_size,
                              hipStream_t stream)
{
    const float* X     = (const float*)d_in[0];
    const float* grid  = (const float*)d_in[1];
    const float* gnorm = (const float*)d_in[2];

    const int N = in_sizes[0] / DIM;

    float* xq   = (float*)d_out;
    void*  idxp = (void*)(xq + (size_t)N * DIM);

    const int blocks = (N + 255) / 256;

    const long xq_elems = (long)N * DIM;
    if ((long)out_size >= xq_elems + N) {
        e8_decode_kernel<2><<<blocks, 256, 0, stream>>>(X, grid, gnorm, xq, idxp, N);
    } else if ((long)out_size > xq_elems) {
        e8_decode_kernel<1><<<blocks, 256, 0, stream>>>(X, grid, gnorm, xq, idxp, N);
    } else {
        e8_decode_kernel<0><<<blocks, 256, 0, stream>>>(X, grid, gnorm, xq, idxp, N);
    }
}

// Round 3
// 100.252 us; speedup vs baseline: 1.5420x; 1.0423x over previous
//
#include <hip/hip_runtime.h>
#include <stdint.h>

// E8P 256-codeword quantizer, analytic decode. Round 3: shrink the fallback
// straggler tail (tighter tie threshold + MLP-unrolled fallback loop).
//
// Codebook structure (compile-time known from the reference builder):
//   idx   0..112 : integer E8 points: zero vector + all +-e_i +- e_j (i<j),
//                  ranked by cartesian_prod key over digits {-2,-1,0,1}.
//   idx 113..240 : half points: all coords +-0.5, even # of negatives.
//   idx 241..255 : 15 extra rows = 5 bases x tails {5,6,7}.
//
// scores s_c = 2 x.g_c - ||g_c||^2. Class maxima in closed form:
//   pair : 2(a(1)+a(2)) - 2          (a = |x|, top-2)
//   zero : 0
//   half : sum|x| - 2               (minus 2*min|x| if sign-parity odd)
//   extra: 2(max base + max tail) - 4
// Near-tie guard: if best - runnerup <= 6.4e-5 (or any x_d == +-0), fall back
// to the brute force (bit-identical to the round-1 loop, absmax==0 verified)
// for that lane. Rounding bound |analytic - ref| <= ~1.5e-5 at 6-sigma inputs.

#define DIM 8
#define NCODES 256

struct Tables {
    unsigned char pair_idx[256]; // [((lo*8+hi)*2+neg_lo)*2+neg_hi]
    unsigned char half_idx[256]; // [negmask]; even-parity entries valid
    unsigned char zero_idx;
};

constexpr Tables make_tables() {
    Tables t{};
    // ---- integer block: zero + 112 pair points, ranked by lex digit key ----
    unsigned key[113] = {};
    int pi[113] = {}, pj[113] = {}, psi[113] = {}, psj[113] = {};
    int n = 0;
    { // zero vector: all digits 2 (value 0)
        unsigned k = 0;
        for (int d = 0; d < 8; ++d) k = k * 4u + 2u;
        key[n] = k; pi[n] = -1; pj[n] = -1; psi[n] = 0; psj[n] = 0; ++n;
    }
    for (int i = 0; i < 8; ++i)
        for (int j = i + 1; j < 8; ++j)
            for (int a = 0; a < 2; ++a)       // a=1 -> coord i is -1 (digit 1), else +1 (digit 3)
                for (int b = 0; b < 2; ++b) {
                    unsigned k = 0;
                    for (int d = 0; d < 8; ++d) {
                        unsigned dig = 2u;
                        if (d == i) dig = a ? 1u : 3u;
                        if (d == j) dig = b ? 1u : 3u;
                        k = k * 4u + dig;
                    }
                    key[n] = k; pi[n] = i; pj[n] = j; psi[n] = a; psj[n] = b; ++n;
                }
    for (int p = 1; p < n; ++p) { // insertion sort by key
        unsigned kk = key[p]; int a = pi[p], b = pj[p], c = psi[p], d2 = psj[p];
        int q = p - 1;
        while (q >= 0 && key[q] > kk) {
            key[q+1]=key[q]; pi[q+1]=pi[q]; pj[q+1]=pj[q]; psi[q+1]=psi[q]; psj[q+1]=psj[q]; --q;
        }
        key[q+1]=kk; pi[q+1]=a; pj[q+1]=b; psi[q+1]=c; psj[q+1]=d2;
    }
    for (int r = 0; r < n; ++r) {
        if (pi[r] < 0) t.zero_idx = (unsigned char)r;
        else t.pair_idx[(((pi[r]*8 + pj[r])*2 + psi[r])*2) + psj[r]] = (unsigned char)r;
    }
    // ---- half block: even-popcount sign masks, digit neg->1, pos->2 ----
    unsigned hkey[128] = {}; int hm[128] = {}; int hn = 0;
    for (int m = 0; m < 256; ++m) {
        int pc = 0; for (int d = 0; d < 8; ++d) pc += (m >> d) & 1;
        if (pc & 1) continue;
        unsigned k = 0;
        for (int d = 0; d < 8; ++d) k = k * 4u + (((m >> d) & 1) ? 1u : 2u);
        hkey[hn] = k; hm[hn] = m; ++hn;
    }
    for (int p = 1; p < hn; ++p) {
        unsigned kk = hkey[p]; int mm = hm[p]; int q = p - 1;
        while (q >= 0 && hkey[q] > kk) { hkey[q+1]=hkey[q]; hm[q+1]=hm[q]; --q; }
        hkey[q+1]=kk; hm[q+1]=mm;
    }
    for (int r = 0; r < hn; ++r) t.half_idx[hm[r]] = (unsigned char)(113 + r);
    return t;
}

constexpr Tables h_tab = make_tables();
__constant__ Tables g_tab = h_tab;

// MODE: 0 = Xq only; 1 = idx as uint8 bytes after Xq; 2 = idx as float after Xq
template <int MODE>
__global__ __launch_bounds__(256)
void e8_decode_kernel(const float* __restrict__ X,
                      const float* __restrict__ grid,
                      const float* __restrict__ gnorm,
                      float* __restrict__ xq_out,
                      void* __restrict__ idx_out,
                      int N)
{
    const long pt = (long)blockIdx.x * blockDim.x + threadIdx.x;
    if (pt >= N) return;

    const float4* xsrc = reinterpret_cast<const float4*>(X + pt * DIM);
    const float4 xa = xsrc[0];
    const float4 xb = xsrc[1];
    float x[8] = {xa.x, xa.y, xa.z, xa.w, xb.x, xb.y, xb.z, xb.w};

    float a[8]; uint32_t sb[8];
    #pragma unroll
    for (int d = 0; d < 8; ++d) {
        const uint32_t u = __float_as_uint(x[d]);
        sb[d] = u >> 31;
        a[d] = __uint_as_float(u & 0x7fffffffu);
    }
    uint32_t mask = 0, par = 0;
    #pragma unroll
    for (int d = 0; d < 8; ++d) { mask |= sb[d] << d; par ^= sb[d]; }
    const bool odd = (par != 0);

    // sequential sum of |x|
    float S = a[0];
    #pragma unroll
    for (int d = 1; d < 8; ++d) S += a[d];

    // min + argmin (first occurrence wins)
    float mn = a[0]; int mi = 0;
    #pragma unroll
    for (int d = 1; d < 8; ++d) { const bool lt = a[d] < mn; mn = lt ? a[d] : mn; mi = lt ? d : mi; }
    float mn2 = 3.0e38f;
    #pragma unroll
    for (int d = 0; d < 8; ++d) { const float v = (d == mi) ? 3.0e38f : a[d]; mn2 = fminf(mn2, v); }

    // top-3 of |x| (indices for top-2)
    float m1 = a[0]; int i1 = 0;
    #pragma unroll
    for (int d = 1; d < 8; ++d) { const bool gt = a[d] > m1; m1 = gt ? a[d] : m1; i1 = gt ? d : i1; }
    float m2 = -3.0e38f; int i2 = 0;
    #pragma unroll
    for (int d = 0; d < 8; ++d) {
        const float v = (d == i1) ? -3.0e38f : a[d];
        const bool gt = v > m2; m2 = gt ? v : m2; i2 = gt ? d : i2;
    }
    float m3 = -3.0e38f;
    #pragma unroll
    for (int d = 0; d < 8; ++d) {
        const float v = (d == i1 || d == i2) ? -3.0e38f : a[d];
        m3 = fmaxf(m3, v);
    }

    // ---- class champion scores ----
    const float s_pair = fmaf(2.0f, m1 + m2, -2.0f);
    const float s_half = odd ? (fmaf(-2.0f, mn, S) - 2.0f) : (S - 2.0f);

    const float y01 = x[0] + x[1];
    float b[5];
    b[0] = y01 + x[2];            // {0,1,2}
    b[1] = y01 + x[4];            // {0,1,4}
    b[2] = (x[0] + x[3]) + x[4];  // {0,3,4}
    b[3] = (x[2] + x[3]) + x[4];  // {2,3,4}
    b[4] = (x[1] + x[2]) + x[3];  // {1,2,3}
    float bm = b[0]; int bi = 0;
    #pragma unroll
    for (int k = 1; k < 5; ++k) { const bool gt = b[k] > bm; bm = gt ? b[k] : bm; bi = gt ? k : bi; }
    float b2nd = -3.0e38f;
    #pragma unroll
    for (int k = 0; k < 5; ++k) { const float v = (k == bi) ? -3.0e38f : b[k]; b2nd = fmaxf(b2nd, v); }
    float tm = x[5]; int ti = 0;
    { const bool gt = x[6] > tm; tm = gt ? x[6] : tm; ti = gt ? 1 : ti; }
    { const bool gt = x[7] > tm; tm = gt ? x[7] : tm; ti = gt ? 2 : ti; }
    const float t2 = fmaxf(fminf(fmaxf(x[5], x[6]), x[7]), fminf(x[5], x[6])); // median of 3
    const float s_extra = fmaf(2.0f, bm + tm, -4.0f);

    // ---- within-class runner-ups for the tie guard ----
    const float r_pair  = fmaf(2.0f, m1 + m3, -2.0f);
    const float r_half  = odd ? (fmaf(-2.0f, mn2, S) - 2.0f)
                              : (fmaf(-2.0f, mn + mn2, S) - 2.0f);
    const float r_extra = fmaf(2.0f, fmaxf(b2nd + tm, bm + t2), -4.0f);

    // ---- codeword indices ----
    const int lo = (i1 < i2) ? i1 : i2;
    const int hi = (i1 < i2) ? i2 : i1;
    const uint32_t slo = (mask >> lo) & 1u;
    const uint32_t shi = (mask >> hi) & 1u;
    const int idx_pair  = g_tab.pair_idx[(((lo << 3) + hi) << 2) + (int)((slo << 1) | shi)];
    const uint32_t hmask = odd ? (mask ^ (1u << mi)) : mask;
    const int idx_half  = g_tab.half_idx[hmask & 255u];
    const int idx_extra = 241 + ti * 5 + bi;
    const int idx_zero  = g_tab.zero_idx;

    // ---- merge 4 candidates; track best / second-best ----
    float best = s_pair; int bidx = idx_pair; float sec = -3.0e38f;
    {
        const float s = 0.0f; const int id = idx_zero;
        const bool gt = s > best;
        const bool take = gt || (s == best && id < bidx);
        sec = fmaxf(sec, gt ? best : s);
        best = gt ? s : best;
        bidx = take ? id : bidx;
    }
    {
        const float s = s_half; const int id = idx_half;
        const bool gt = s > best;
        const bool take = gt || (s == best && id < bidx);
        sec = fmaxf(sec, gt ? best : s);
        best = gt ? s : best;
        bidx = take ? id : bidx;
    }
    {
        const float s = s_extra; const int id = idx_extra;
        const bool gt = s > best;
        const bool take = gt || (s == best && id < bidx);
        sec = fmaxf(sec, gt ? best : s);
        best = gt ? s : best;
        bidx = take ? id : bidx;
    }
    sec = fmaxf(fmaxf(sec, r_pair), fmaxf(r_half, r_extra));

    // ---- near-tie / degenerate guard: brute-force those lanes ----
    // tau = 6.4e-5: >=4x the worst-case analytic-vs-einsum rounding gap (~1.5e-5
    // at 6-sigma inputs), ~3x fewer triggers than round-2's 2e-4.
    const bool fb = !((best - sec) > 6.4e-5f) || !(mn > 0.0f);
    if (__any(fb)) {
        if (fb) {
            float2 xv[4];
            #pragma unroll
            for (int q = 0; q < 4; ++q)
                xv[q] = make_float2(2.0f * x[2*q], 2.0f * x[2*q + 1]);
            float bb = -3.4e38f; int bbi = 0;
            // Unrolled x4: 4 uniform codebook rows in flight (scalar-load MLP)
            // instead of one dependent load chain per iteration. Per-codeword
            // arithmetic identical to the round-1 verified loop.
            for (int c = 0; c < NCODES; c += 4) {
                float s[4];
                #pragma unroll
                for (int u = 0; u < 4; ++u) {
                    const float2* g2 = reinterpret_cast<const float2*>(grid + (c + u) * DIM);
                    float2 acc = xv[0] * g2[0];
                    acc += xv[1] * g2[1];
                    acc += xv[2] * g2[2];
                    acc += xv[3] * g2[3];
                    s[u] = (acc.x + acc.y) - gnorm[c + u];
                }
                #pragma unroll
                for (int u = 0; u < 4; ++u) {   // sequential merge: first-max wins
                    const bool gt = s[u] > bb;
                    bb = gt ? s[u] : bb; bbi = gt ? c + u : bbi;
                }
            }
            bidx = bbi;
        }
    }

    // ---- outputs ----
    const float4* gr = reinterpret_cast<const float4*>(grid + (long)bidx * DIM);
    const float4 q0 = gr[0];
    const float4 q1 = gr[1];
    float4* dst = reinterpret_cast<float4*>(xq_out + pt * DIM);
    dst[0] = q0;
    dst[1] = q1;
    if (MODE == 2) {
        reinterpret_cast<float*>(idx_out)[pt] = (float)bidx;
    } else if (MODE == 1) {
        reinterpret_cast<uint8_t*>(idx_out)[pt] = (uint8_t)bidx;
    }
}

extern "C" void kernel_launch(void* const* d_in, const int* in_sizes, int n_in,
                              void* d_out, int out_size, void* d_ws, size_t ws_size,
                              hipStream_t stream)
{
    const float* X     = (const float*)d_in[0];
    const float* grid  = (const float*)d_in[1];
    const float* gnorm = (const float*)d_in[2];

    const int N = in_sizes[0] / DIM;

    float* xq   = (float*)d_out;
    void*  idxp = (void*)(xq + (size_t)N * DIM);

    const int blocks = (N + 255) / 256;

    const long xq_elems = (long)N * DIM;
    if ((long)out_size >= xq_elems + N) {
        e8_decode_kernel<2><<<blocks, 256, 0, stream>>>(X, grid, gnorm, xq, idxp, N);
    } else if ((long)out_size > xq_elems) {
        e8_decode_kernel<1><<<blocks, 256, 0, stream>>>(X, grid, gnorm, xq, idxp, N);
    } else {
        e8_decode_kernel<0><<<blocks, 256, 0, stream>>>(X, grid, gnorm, xq, idxp, N);
    }
}

// Round 4
// 89.053 us; speedup vs baseline: 1.7360x; 1.1258x over previous
//
#include <hip/hip_runtime.h>
#include <stdint.h>

// E8P 256-codeword quantizer, analytic decode. Round 4: wave-cooperative
// fallback (kills the straggler-wave tail; previously one near-tie lane made
// its whole wave run a serialized ~5.5us 256-codeword scan).
//
// Codebook structure (compile-time known from the reference builder):
//   idx   0..112 : integer E8 points: zero vector + all +-e_i +- e_j (i<j),
//                  ranked by cartesian_prod key over digits {-2,-1,0,1}.
//   idx 113..240 : half points: all coords +-0.5, even # of negatives.
//   idx 241..255 : 15 extra rows = 5 bases x tails {5,6,7}.
//
// scores s_c = 2 x.g_c - ||g_c||^2. Class maxima in closed form:
//   pair : 2(a(1)+a(2)) - 2          (a = |x|, top-2)
//   zero : 0
//   half : sum|x| - 2               (minus 2*min|x| if sign-parity odd)
//   extra: 2(max base + max tail) - 4
// Near-tie guard: if best - runnerup <= 6.4e-5 (or any x_d == +-0), that
// point is re-scored by the WHOLE WAVE: broadcast x, 64 lanes x 4 codewords,
// butterfly argmax reduce (lower index wins ties == jnp.argmax first-max).
// Per-codeword arithmetic bit-identical to the round-1 brute force
// (verified absmax==0 on all 1M points).

#define DIM 8
#define NCODES 256

struct Tables {
    unsigned char pair_idx[256]; // [((lo*8+hi)*2+neg_lo)*2+neg_hi]
    unsigned char half_idx[256]; // [negmask]; even-parity entries valid
    unsigned char zero_idx;
};

constexpr Tables make_tables() {
    Tables t{};
    // ---- integer block: zero + 112 pair points, ranked by lex digit key ----
    unsigned key[113] = {};
    int pi[113] = {}, pj[113] = {}, psi[113] = {}, psj[113] = {};
    int n = 0;
    { // zero vector: all digits 2 (value 0)
        unsigned k = 0;
        for (int d = 0; d < 8; ++d) k = k * 4u + 2u;
        key[n] = k; pi[n] = -1; pj[n] = -1; psi[n] = 0; psj[n] = 0; ++n;
    }
    for (int i = 0; i < 8; ++i)
        for (int j = i + 1; j < 8; ++j)
            for (int a = 0; a < 2; ++a)       // a=1 -> coord i is -1 (digit 1), else +1 (digit 3)
                for (int b = 0; b < 2; ++b) {
                    unsigned k = 0;
                    for (int d = 0; d < 8; ++d) {
                        unsigned dig = 2u;
                        if (d == i) dig = a ? 1u : 3u;
                        if (d == j) dig = b ? 1u : 3u;
                        k = k * 4u + dig;
                    }
                    key[n] = k; pi[n] = i; pj[n] = j; psi[n] = a; psj[n] = b; ++n;
                }
    for (int p = 1; p < n; ++p) { // insertion sort by key
        unsigned kk = key[p]; int a = pi[p], b = pj[p], c = psi[p], d2 = psj[p];
        int q = p - 1;
        while (q >= 0 && key[q] > kk) {
            key[q+1]=key[q]; pi[q+1]=pi[q]; pj[q+1]=pj[q]; psi[q+1]=psi[q]; psj[q+1]=psj[q]; --q;
        }
        key[q+1]=kk; pi[q+1]=a; pj[q+1]=b; psi[q+1]=c; psj[q+1]=d2;
    }
    for (int r = 0; r < n; ++r) {
        if (pi[r] < 0) t.zero_idx = (unsigned char)r;
        else t.pair_idx[(((pi[r]*8 + pj[r])*2 + psi[r])*2) + psj[r]] = (unsigned char)r;
    }
    // ---- half block: even-popcount sign masks, digit neg->1, pos->2 ----
    unsigned hkey[128] = {}; int hm[128] = {}; int hn = 0;
    for (int m = 0; m < 256; ++m) {
        int pc = 0; for (int d = 0; d < 8; ++d) pc += (m >> d) & 1;
        if (pc & 1) continue;
        unsigned k = 0;
        for (int d = 0; d < 8; ++d) k = k * 4u + (((m >> d) & 1) ? 1u : 2u);
        hkey[hn] = k; hm[hn] = m; ++hn;
    }
    for (int p = 1; p < hn; ++p) {
        unsigned kk = hkey[p]; int mm = hm[p]; int q = p - 1;
        while (q >= 0 && hkey[q] > kk) { hkey[q+1]=hkey[q]; hm[q+1]=hm[q]; --q; }
        hkey[q+1]=kk; hm[q+1]=mm;
    }
    for (int r = 0; r < hn; ++r) t.half_idx[hm[r]] = (unsigned char)(113 + r);
    return t;
}

constexpr Tables h_tab = make_tables();
__constant__ Tables g_tab = h_tab;

// MODE: 0 = Xq only; 1 = idx as uint8 bytes after Xq; 2 = idx as float after Xq
template <int MODE>
__global__ __launch_bounds__(256)
void e8_decode_kernel(const float* __restrict__ X,
                      const float* __restrict__ grid,
                      const float* __restrict__ gnorm,
                      float* __restrict__ xq_out,
                      void* __restrict__ idx_out,
                      int N)
{
    const long pt = (long)blockIdx.x * blockDim.x + threadIdx.x;
    if (pt >= N) return;
    const int lane = threadIdx.x & 63;

    const float4* xsrc = reinterpret_cast<const float4*>(X + pt * DIM);
    const float4 xa = xsrc[0];
    const float4 xb = xsrc[1];
    float x[8] = {xa.x, xa.y, xa.z, xa.w, xb.x, xb.y, xb.z, xb.w};

    float a[8]; uint32_t sb[8];
    #pragma unroll
    for (int d = 0; d < 8; ++d) {
        const uint32_t u = __float_as_uint(x[d]);
        sb[d] = u >> 31;
        a[d] = __uint_as_float(u & 0x7fffffffu);
    }
    uint32_t mask = 0, par = 0;
    #pragma unroll
    for (int d = 0; d < 8; ++d) { mask |= sb[d] << d; par ^= sb[d]; }
    const bool odd = (par != 0);

    // sequential sum of |x|
    float S = a[0];
    #pragma unroll
    for (int d = 1; d < 8; ++d) S += a[d];

    // min + argmin (first occurrence wins)
    float mn = a[0]; int mi = 0;
    #pragma unroll
    for (int d = 1; d < 8; ++d) { const bool lt = a[d] < mn; mn = lt ? a[d] : mn; mi = lt ? d : mi; }
    float mn2 = 3.0e38f;
    #pragma unroll
    for (int d = 0; d < 8; ++d) { const float v = (d == mi) ? 3.0e38f : a[d]; mn2 = fminf(mn2, v); }

    // top-3 of |x| (indices for top-2)
    float m1 = a[0]; int i1 = 0;
    #pragma unroll
    for (int d = 1; d < 8; ++d) { const bool gt = a[d] > m1; m1 = gt ? a[d] : m1; i1 = gt ? d : i1; }
    float m2 = -3.0e38f; int i2 = 0;
    #pragma unroll
    for (int d = 0; d < 8; ++d) {
        const float v = (d == i1) ? -3.0e38f : a[d];
        const bool gt = v > m2; m2 = gt ? v : m2; i2 = gt ? d : i2;
    }
    float m3 = -3.0e38f;
    #pragma unroll
    for (int d = 0; d < 8; ++d) {
        const float v = (d == i1 || d == i2) ? -3.0e38f : a[d];
        m3 = fmaxf(m3, v);
    }

    // ---- class champion scores ----
    const float s_pair = fmaf(2.0f, m1 + m2, -2.0f);
    const float s_half = odd ? (fmaf(-2.0f, mn, S) - 2.0f) : (S - 2.0f);

    const float y01 = x[0] + x[1];
    float b[5];
    b[0] = y01 + x[2];            // {0,1,2}
    b[1] = y01 + x[4];            // {0,1,4}
    b[2] = (x[0] + x[3]) + x[4];  // {0,3,4}
    b[3] = (x[2] + x[3]) + x[4];  // {2,3,4}
    b[4] = (x[1] + x[2]) + x[3];  // {1,2,3}
    float bm = b[0]; int bi = 0;
    #pragma unroll
    for (int k = 1; k < 5; ++k) { const bool gt = b[k] > bm; bm = gt ? b[k] : bm; bi = gt ? k : bi; }
    float b2nd = -3.0e38f;
    #pragma unroll
    for (int k = 0; k < 5; ++k) { const float v = (k == bi) ? -3.0e38f : b[k]; b2nd = fmaxf(b2nd, v); }
    float tm = x[5]; int ti = 0;
    { const bool gt = x[6] > tm; tm = gt ? x[6] : tm; ti = gt ? 1 : ti; }
    { const bool gt = x[7] > tm; tm = gt ? x[7] : tm; ti = gt ? 2 : ti; }
    const float t2 = fmaxf(fminf(fmaxf(x[5], x[6]), x[7]), fminf(x[5], x[6])); // median of 3
    const float s_extra = fmaf(2.0f, bm + tm, -4.0f);

    // ---- within-class runner-ups for the tie guard ----
    const float r_pair  = fmaf(2.0f, m1 + m3, -2.0f);
    const float r_half  = odd ? (fmaf(-2.0f, mn2, S) - 2.0f)
                              : (fmaf(-2.0f, mn + mn2, S) - 2.0f);
    const float r_extra = fmaf(2.0f, fmaxf(b2nd + tm, bm + t2), -4.0f);

    // ---- codeword indices ----
    const int lo = (i1 < i2) ? i1 : i2;
    const int hi = (i1 < i2) ? i2 : i1;
    const uint32_t slo = (mask >> lo) & 1u;
    const uint32_t shi = (mask >> hi) & 1u;
    const int idx_pair  = g_tab.pair_idx[(((lo << 3) + hi) << 2) + (int)((slo << 1) | shi)];
    const uint32_t hmask = odd ? (mask ^ (1u << mi)) : mask;
    const int idx_half  = g_tab.half_idx[hmask & 255u];
    const int idx_extra = 241 + ti * 5 + bi;
    const int idx_zero  = g_tab.zero_idx;

    // ---- merge 4 candidates; track best / second-best ----
    float best = s_pair; int bidx = idx_pair; float sec = -3.0e38f;
    {
        const float s = 0.0f; const int id = idx_zero;
        const bool gt = s > best;
        const bool take = gt || (s == best && id < bidx);
        sec = fmaxf(sec, gt ? best : s);
        best = gt ? s : best;
        bidx = take ? id : bidx;
    }
    {
        const float s = s_half; const int id = idx_half;
        const bool gt = s > best;
        const bool take = gt || (s == best && id < bidx);
        sec = fmaxf(sec, gt ? best : s);
        best = gt ? s : best;
        bidx = take ? id : bidx;
    }
    {
        const float s = s_extra; const int id = idx_extra;
        const bool gt = s > best;
        const bool take = gt || (s == best && id < bidx);
        sec = fmaxf(sec, gt ? best : s);
        best = gt ? s : best;
        bidx = take ? id : bidx;
    }
    sec = fmaxf(fmaxf(sec, r_pair), fmaxf(r_half, r_extra));

    // ---- near-tie / degenerate guard: wave-cooperative rescore ----
    // tau = 6.4e-5: >=4x the worst-case analytic-vs-einsum rounding gap.
    const bool fb = !((best - sec) > 6.4e-5f) || !(mn > 0.0f);
    uint64_t bal = __ballot(fb);
    while (bal) {
        const int src = __ffsll((unsigned long long)bal) - 1;
        bal &= bal - 1;
        // broadcast the triggering point's coords to all 64 lanes
        float xs[8];
        #pragma unroll
        for (int d = 0; d < 8; ++d) xs[d] = __shfl(x[d], src);
        float2 xv[4];
        #pragma unroll
        for (int q = 0; q < 4; ++q)
            xv[q] = make_float2(2.0f * xs[2*q], 2.0f * xs[2*q + 1]);
        // each lane scores 4 codewords: c = lane*4 + u (ascending, strict >)
        float bb = -3.4e38f; int bbi = 0;
        #pragma unroll
        for (int u = 0; u < 4; ++u) {
            const int c = (lane << 2) + u;
            const float2* g2 = reinterpret_cast<const float2*>(grid + c * DIM);
            float2 acc = xv[0] * g2[0];   // bit-identical to the round-1 loop
            acc += xv[1] * g2[1];
            acc += xv[2] * g2[2];
            acc += xv[3] * g2[3];
            const float s = (acc.x + acc.y) - gnorm[c];
            const bool gt = s > bb;
            bb = gt ? s : bb; bbi = gt ? c : bbi;
        }
        // butterfly argmax reduce; lower index wins ties (jnp.argmax first-max)
        #pragma unroll
        for (int off = 32; off >= 1; off >>= 1) {
            const float so = __shfl_xor(bb, off);
            const int   io = __shfl_xor(bbi, off);
            const bool take = (so > bb) || (so == bb && io < bbi);
            bb  = take ? so : bb;
            bbi = take ? io : bbi;
        }
        if (lane == src) bidx = bbi;
    }

    // ---- outputs ----
    const float4* gr = reinterpret_cast<const float4*>(grid + (long)bidx * DIM);
    const float4 q0 = gr[0];
    const float4 q1 = gr[1];
    float4* dst = reinterpret_cast<float4*>(xq_out + pt * DIM);
    dst[0] = q0;
    dst[1] = q1;
    if (MODE == 2) {
        reinterpret_cast<float*>(idx_out)[pt] = (float)bidx;
    } else if (MODE == 1) {
        reinterpret_cast<uint8_t*>(idx_out)[pt] = (uint8_t)bidx;
    }
}

extern "C" void kernel_launch(void* const* d_in, const int* in_sizes, int n_in,
                              void* d_out, int out_size, void* d_ws, size_t ws_size,
                              hipStream_t stream)
{
    const float* X     = (const float*)d_in[0];
    const float* grid  = (const float*)d_in[1];
    const float* gnorm = (const float*)d_in[2];

    const int N = in_sizes[0] / DIM;

    float* xq   = (float*)d_out;
    void*  idxp = (void*)(xq + (size_t)N * DIM);

    const int blocks = (N + 255) / 256;

    const long xq_elems = (long)N * DIM;
    if ((long)out_size >= xq_elems + N) {
        e8_decode_kernel<2><<<blocks, 256, 0, stream>>>(X, grid, gnorm, xq, idxp, N);
    } else if ((long)out_size > xq_elems) {
        e8_decode_kernel<1><<<blocks, 256, 0, stream>>>(X, grid, gnorm, xq, idxp, N);
    } else {
        e8_decode_kernel<0><<<blocks, 256, 0, stream>>>(X, grid, gnorm, xq, idxp, N);
    }
}